// Round 11
// baseline (70.148 us; speedup 1.0000x reference)
//
#include <hip/hip_runtime.h>

#define EPSF 0.01f
#define THREADS 256
#define WAVES (THREADS / 64)
#define TILE (THREADS * 4)     // 1024 elems: thread t -> 4 elems at tb+4t
#define TPB_P 16               // pack tiles/block  -> PCH = 16384
#define PCH (TILE * TPB_P)
#define TPB_E 32               // emit tiles/block  -> ECH = 32768 (= 2 PCH)
#define ECH (TILE * TPB_E)
#define GROUPS_P 2             // uint4 code groups per pack block (8 tiles each)
#define GROUPS_E 4             // code groups per emit block

typedef unsigned long long u64;
typedef unsigned int u32;
typedef int i32x4 __attribute__((ext_vector_type(4)));
typedef float f32x4 __attribute__((ext_vector_type(4)));

// Per-category change scalars, exactly as the reference computes them.
// jnp.clip(x, lo, hi) == min(max(x, lo), hi)
__device__ __forceinline__ void load_changes(const float* bd, const float* de,
                                             const float* sa, const float* in,
                                             const float* bi, float ch[5]) {
    float vbd = *bd, vd = *de, vs = *sa, vi = *in, vbi = *bi;
    ch[0] = fminf(vbd, fminf(0.0f, vd) - EPSF);
    ch[1] = fminf(fmaxf(vd, vbd + EPSF), 0.0f - EPSF);
    ch[2] = fminf(fmaxf(vs, vd + EPSF), vi - EPSF);
    ch[3] = fminf(fmaxf(vi, 0.0f + EPSF), vbi - EPSF);
    ch[4] = fmaxf(vbi, fmaxf(0.0f, vi) + EPSF);
}

// code 0..4 -> change; cmp+cndmask chain (no runtime-indexed array).
__device__ __forceinline__ float selc(u32 v, float c0, float c1, float c2,
                                      float c3, float c4) {
    return (v == 0) ? c0 : (v == 1) ? c1 : (v == 2) ? c2 : (v == 3) ? c3 : c4;
}

// Pass 1 (np=2048 blocks, 16384 elems each): NONTEMPORAL coalesced int4 reads
// of ann (touch-once -> don't evict codes from L2/IC), pack 4-bit codes as
// uint4/thread/8-tile-group (coalesced, cached -- k_emit re-reads them), exact
// per-block counts via packed 12-bit fields -> bcT[c*np+b].
__global__ __launch_bounds__(THREADS) void k_pack(const int* __restrict__ ann,
                                                  uint4* __restrict__ c4,
                                                  int* __restrict__ bcT,
                                                  long long n, int np) {
    const int tid = threadIdx.x, lane = tid & 63, wv = tid >> 6;
    const long long start = (long long)blockIdx.x * PCH;
    u64 pk = 0ull;

    for (int g = 0; g < GROUPS_P; ++g) {
        long long gb = start + (long long)g * (8 * TILE);
        if (gb >= n) break;  // block-uniform
        u32 w0 = 0, w1 = 0, w2 = 0, w3 = 0;
#pragma unroll
        for (int tt = 0; tt < 8; ++tt) {
            long long tb = gb + (long long)tt * TILE;
            if (tb >= n) break;  // block-uniform
            long long i = tb + (long long)tid * 4;
            u32 nib = 0;
            if (i + 4 <= n) {
                i32x4 a = __builtin_nontemporal_load(
                    reinterpret_cast<const i32x4*>(ann + i));
                u32 cx = (u32)(a.x - 1), cy = (u32)(a.y - 1);
                u32 cz = (u32)(a.z - 1), cd = (u32)(a.w - 1);
                pk += (1ull << (cx * 12)) + (1ull << (cy * 12)) +
                      (1ull << (cz * 12)) + (1ull << (cd * 12));
                nib = cx | (cy << 4) | (cz << 8) | (cd << 12);
            } else {
#pragma unroll
                for (int j = 0; j < 4; ++j) {
                    if (i + j < n) {
                        u32 c = (u32)(ann[i + j] - 1);
                        pk += (1ull << (c * 12));
                        nib |= c << (4 * j);
                    }
                }
            }
            u32 sh = (tt & 1) * 16;
            if (tt < 2) w0 |= nib << sh;
            else if (tt < 4) w1 |= nib << sh;
            else if (tt < 6) w2 |= nib << sh;
            else w3 |= nib << sh;
        }
        c4[((long long)blockIdx.x * GROUPS_P + g) * THREADS + tid] =
            make_uint4(w0, w1, w2, w3);
    }

    int cnt[5];
#pragma unroll
    for (int c = 0; c < 5; ++c) cnt[c] = (int)((pk >> (c * 12)) & 0xFFFull);
    __shared__ int sred[WAVES][5];
#pragma unroll
    for (int c = 0; c < 5; ++c) {
        int s = cnt[c];
#pragma unroll
        for (int off = 32; off > 0; off >>= 1) s += __shfl_down(s, off, 64);
        if (lane == 0) sred[wv][c] = s;
    }
    __syncthreads();
    if (tid == 0) {
#pragma unroll
        for (int c = 0; c < 5; ++c)
            bcT[c * np + blockIdx.x] =
                sred[0][c] + sred[1][c] + sred[2][c] + sred[3][c];
    }
}

// Pass 2 (ne=1024 fatter blocks, 32768 elems each -> half the Phase-A
// redundancy): exact base from pack-granularity predecessor counts
// (emit block e sums pack blocks j < 2e), then R9's proven block-cooperative
// tile loop: decode codes from registers, wave scan + double-buffered wsum
// (1 barrier/tile), NONTEMPORAL coalesced float4 exclusive-prefix stores.
__global__ __launch_bounds__(THREADS) void k_emit(
    const uint4* __restrict__ c4, const int* __restrict__ bcT,
    float* __restrict__ out, long long n, int np, int ne, const float* org,
    const float* bd, const float* de, const float* sa, const float* in,
    const float* bi) {
    float ch[5];
    load_changes(bd, de, sa, in, bi, ch);
    const float c0 = ch[0], c1 = ch[1], c2 = ch[2], c3 = ch[3], c4v = ch[4];

    __shared__ int sred[WAVES][5];
    __shared__ float wsum[2][WAVES];
    __shared__ float s_base;

    const int tid = threadIdx.x, lane = tid & 63, wv = tid >> 6;
    const int vbid = blockIdx.x;
    const int npred = 2 * vbid;  // pack blocks preceding my chunk

    // Phase A: base = org + sum_c (#cat_c in pack blocks < 2*vbid) * ch_c
    int pc[5];
#pragma unroll
    for (int c = 0; c < 5; ++c) {
        int s = 0;
        for (int j = tid; j < npred; j += THREADS) s += bcT[c * np + j];
#pragma unroll
        for (int off = 32; off > 0; off >>= 1) s += __shfl_down(s, off, 64);
        pc[c] = s;
    }
    if (lane == 0) {
#pragma unroll
        for (int c = 0; c < 5; ++c) sred[wv][c] = pc[c];
    }
    __syncthreads();
    if (tid == 0) {
        double acc = (double)(*org);
#pragma unroll
        for (int c = 0; c < 5; ++c) {
            int tot = sred[0][c] + sred[1][c] + sred[2][c] + sred[3][c];
            acc += (double)tot * (double)ch[c];
        }
        s_base = (float)acc;
    }
    __syncthreads();

    const long long start = (long long)vbid * ECH;
    long long end = start + ECH;
    if (end > n) end = n;
    float running = s_base;

    for (int g = 0; g < GROUPS_E; ++g) {
        long long gb = start + (long long)g * (8 * TILE);
        if (gb >= end) break;  // block-uniform
        uint4 cv = c4[((long long)vbid * GROUPS_E + g) * THREADS + tid];
#pragma unroll
        for (int tt = 0; tt < 8; ++tt) {
            long long tb = gb + (long long)tt * TILE;
            if (tb >= end) break;  // block-uniform
            long long i = tb + (long long)tid * 4;

            u32 w = (tt < 2) ? cv.x : (tt < 4) ? cv.y : (tt < 6) ? cv.z : cv.w;
            u32 nib = w >> ((tt & 1) * 16);
            const bool vec = (i + 4 <= n);
            float d0 = selc(nib & 0xF, c0, c1, c2, c3, c4v);
            float d1 = selc((nib >> 4) & 0xF, c0, c1, c2, c3, c4v);
            float d2 = selc((nib >> 8) & 0xF, c0, c1, c2, c3, c4v);
            float d3 = selc((nib >> 12) & 0xF, c0, c1, c2, c3, c4v);
            if (!vec) {
                if (i + 0 >= n) d0 = 0.0f;
                if (i + 1 >= n) d1 = 0.0f;
                if (i + 2 >= n) d2 = 0.0f;
                if (i + 3 >= n) d3 = 0.0f;
            }
            float e1 = d0, e2 = e1 + d1, e3 = e2 + d2, s = e3 + d3;

            float x = s;
#pragma unroll
            for (int off = 1; off < 64; off <<= 1) {
                float y = __shfl_up(x, off, 64);
                if (lane >= off) x += y;
            }
            if (lane == 63) wsum[tt & 1][wv] = x;
            __syncthreads();
            float w0 = wsum[tt & 1][0], w1 = wsum[tt & 1][1];
            float w2 = wsum[tt & 1][2], w3 = wsum[tt & 1][3];
            float waveOff = (wv > 0 ? w0 : 0.0f) + (wv > 1 ? w1 : 0.0f) +
                            (wv > 2 ? w2 : 0.0f);
            float total = w0 + w1 + w2 + w3;
            // next tile uses the OTHER wsum slot (R7/R9-proven)

            float b = running + waveOff + (x - s);
            if (vec) {
                f32x4 v = {b, b + e1, b + e2, b + e3};
                __builtin_nontemporal_store(
                    v, reinterpret_cast<f32x4*>(out + i));
            } else {
                if (i + 0 < n) out[i + 0] = b;
                if (i + 1 < n) out[i + 1] = b + e1;
                if (i + 2 < n) out[i + 2] = b + e2;
                if (i + 3 < n) out[i + 3] = b + e3;
            }
            running += total;
        }
    }
    if (end == n && start < n && tid == 0) out[n] = running;
}

extern "C" void kernel_launch(void* const* d_in, const int* in_sizes, int n_in,
                              void* d_out, int out_size, void* d_ws, size_t ws_size,
                              hipStream_t stream) {
    const int* ann = (const int*)d_in[0];
    const float* org = (const float*)d_in[1];
    const float* bd = (const float*)d_in[2];
    const float* de = (const float*)d_in[3];
    const float* sa = (const float*)d_in[4];
    const float* in = (const float*)d_in[5];
    const float* bi = (const float*)d_in[6];
    float* out = (float*)d_out;

    long long n = (long long)in_sizes[0];
    int np = (int)((n + PCH - 1) / PCH);  // 2048 for N=2^25
    if (np < 1) np = 1;
    int ne = (int)((n + ECH - 1) / ECH);  // 1024 for N=2^25
    if (ne < 1) ne = 1;

    // ws layout: bcT (np*5 ints) | codes (np*GROUPS_P*THREADS uint4)
    int* bcT = (int*)d_ws;
    size_t bct_bytes = ((size_t)np * 5 * sizeof(int) + 255) & ~(size_t)255;
    uint4* c4 = (uint4*)((char*)d_ws + bct_bytes);

    k_pack<<<np, THREADS, 0, stream>>>(ann, c4, bcT, n, np);
    k_emit<<<ne, THREADS, 0, stream>>>(c4, bcT, out, n, np, ne, org, bd, de,
                                       sa, in, bi);
}

// Round 12
// 65.143 us; speedup vs baseline: 1.0768x; 1.0768x over previous
//
#include <hip/hip_runtime.h>

#define EPSF 0.01f
#define THREADS 256
#define WAVES (THREADS / 64)
#define TILE (THREADS * 4)   // 1024 elems: thread t -> 4 elems at tb+4t (coalesced)
#define TPB 16               // tiles per block -> chunk = 16384
#define CHUNK (TILE * TPB)
#define GROUPS 2             // 8 tiles per uint4 code group

typedef unsigned long long u64;
typedef unsigned int u32;
typedef int i32x4 __attribute__((ext_vector_type(4)));

// Per-category change scalars, exactly as the reference computes them.
// jnp.clip(x, lo, hi) == min(max(x, lo), hi)
__device__ __forceinline__ void load_changes(const float* bd, const float* de,
                                             const float* sa, const float* in,
                                             const float* bi, float ch[5]) {
    float vbd = *bd, vd = *de, vs = *sa, vi = *in, vbi = *bi;
    ch[0] = fminf(vbd, fminf(0.0f, vd) - EPSF);
    ch[1] = fminf(fmaxf(vd, vbd + EPSF), 0.0f - EPSF);
    ch[2] = fminf(fmaxf(vs, vd + EPSF), vi - EPSF);
    ch[3] = fminf(fmaxf(vi, 0.0f + EPSF), vbi - EPSF);
    ch[4] = fmaxf(vbi, fmaxf(0.0f, vi) + EPSF);
}

// code 0..4 -> change; cmp+cndmask chain (no runtime-indexed array).
__device__ __forceinline__ float selc(u32 v, float c0, float c1, float c2,
                                      float c3, float c4) {
    return (v == 0) ? c0 : (v == 1) ? c1 : (v == 2) ? c2 : (v == 3) ? c3 : c4;
}

// Pass 1: read ann once -- NONTEMPORAL (touch-once stream; keep it from
// evicting the 17 MB code array from L2/IC between kernels). Pack 4-bit codes
// as uint4/thread/8-tile-group (coalesced, normal cached store) + exact
// per-block counts (12-bit packed fields) -> bcT[c*nb+b].
__global__ __launch_bounds__(THREADS) void k_pack(const int* __restrict__ ann,
                                                  uint4* __restrict__ c4,
                                                  int* __restrict__ bcT,
                                                  long long n, int nb) {
    const int tid = threadIdx.x, lane = tid & 63, wv = tid >> 6;
    const long long start = (long long)blockIdx.x * CHUNK;
    u64 pk = 0ull;

    for (int g = 0; g < GROUPS; ++g) {
        long long gb = start + (long long)g * (8 * TILE);
        if (gb >= n) break;  // block-uniform
        u32 w0 = 0, w1 = 0, w2 = 0, w3 = 0;
#pragma unroll
        for (int tt = 0; tt < 8; ++tt) {
            long long tb = gb + (long long)tt * TILE;
            if (tb >= n) break;  // block-uniform
            long long i = tb + (long long)tid * 4;
            u32 nib = 0;
            if (i + 4 <= n) {
                i32x4 a = __builtin_nontemporal_load(
                    reinterpret_cast<const i32x4*>(ann + i));
                u32 cx = (u32)(a.x - 1), cy = (u32)(a.y - 1);
                u32 cz = (u32)(a.z - 1), cd = (u32)(a.w - 1);
                pk += (1ull << (cx * 12)) + (1ull << (cy * 12)) +
                      (1ull << (cz * 12)) + (1ull << (cd * 12));
                nib = cx | (cy << 4) | (cz << 8) | (cd << 12);
            } else {
#pragma unroll
                for (int j = 0; j < 4; ++j) {
                    if (i + j < n) {
                        u32 c = (u32)(ann[i + j] - 1);
                        pk += (1ull << (c * 12));
                        nib |= c << (4 * j);
                    }
                }
            }
            u32 sh = (tt & 1) * 16;
            if (tt < 2) w0 |= nib << sh;
            else if (tt < 4) w1 |= nib << sh;
            else if (tt < 6) w2 |= nib << sh;
            else w3 |= nib << sh;
        }
        c4[((long long)blockIdx.x * GROUPS + g) * THREADS + tid] =
            make_uint4(w0, w1, w2, w3);
    }

    int cnt[5];
#pragma unroll
    for (int c = 0; c < 5; ++c) cnt[c] = (int)((pk >> (c * 12)) & 0xFFFull);
    __shared__ int sred[WAVES][5];
#pragma unroll
    for (int c = 0; c < 5; ++c) {
        int s = cnt[c];
#pragma unroll
        for (int off = 32; off > 0; off >>= 1) s += __shfl_down(s, off, 64);
        if (lane == 0) sred[wv][c] = s;
    }
    __syncthreads();
    if (tid == 0) {
#pragma unroll
        for (int c = 0; c < 5; ++c)
            bcT[c * nb + blockIdx.x] =
                sred[0][c] + sred[1][c] + sred[2][c] + sred[3][c];
    }
}

// Pass 2 (exact R9): exact float base via redundant predecessor-count sum
// (40 KB, L2/IC-resident, fully parallel), then per tile: decode codes from
// registers, wave scan + double-buffered wsum (1 barrier/tile), coalesced
// float4 exclusive-prefix stores (normal cached stores).
__global__ __launch_bounds__(THREADS) void k_emit(
    const uint4* __restrict__ c4, const int* __restrict__ bcT,
    float* __restrict__ out, long long n, int nb, const float* org,
    const float* bd, const float* de, const float* sa, const float* in,
    const float* bi) {
    float ch[5];
    load_changes(bd, de, sa, in, bi, ch);
    const float c0 = ch[0], c1 = ch[1], c2 = ch[2], c3 = ch[3], c4v = ch[4];

    __shared__ int sred[WAVES][5];
    __shared__ float wsum[2][WAVES];  // double-buffered: 1 barrier per tile
    __shared__ float s_base;

    const int tid = threadIdx.x, lane = tid & 63, wv = tid >> 6;
    const int vbid = blockIdx.x;

    // Phase A: base = org + sum_c (#cat_c before my chunk) * ch_c (exact ints)
    int pc[5];
#pragma unroll
    for (int c = 0; c < 5; ++c) {
        int s = 0;
        for (int j = tid; j < vbid; j += THREADS) s += bcT[c * nb + j];
#pragma unroll
        for (int off = 32; off > 0; off >>= 1) s += __shfl_down(s, off, 64);
        pc[c] = s;
    }
    if (lane == 0) {
#pragma unroll
        for (int c = 0; c < 5; ++c) sred[wv][c] = pc[c];
    }
    __syncthreads();
    if (tid == 0) {
        double acc = (double)(*org);
#pragma unroll
        for (int c = 0; c < 5; ++c) {
            int tot = sred[0][c] + sred[1][c] + sred[2][c] + sred[3][c];
            acc += (double)tot * (double)ch[c];
        }
        s_base = (float)acc;
    }
    __syncthreads();

    const long long start = (long long)vbid * CHUNK;
    long long end = start + CHUNK;
    if (end > n) end = n;
    float running = s_base;

    for (int g = 0; g < GROUPS; ++g) {
        long long gb = start + (long long)g * (8 * TILE);
        if (gb >= end) break;  // block-uniform
        uint4 cv = c4[((long long)vbid * GROUPS + g) * THREADS + tid];
#pragma unroll
        for (int tt = 0; tt < 8; ++tt) {
            long long tb = gb + (long long)tt * TILE;
            if (tb >= end) break;  // block-uniform
            long long i = tb + (long long)tid * 4;

            u32 w = (tt < 2) ? cv.x : (tt < 4) ? cv.y : (tt < 6) ? cv.z : cv.w;
            u32 nib = w >> ((tt & 1) * 16);
            const bool vec = (i + 4 <= n);
            float d0 = selc(nib & 0xF, c0, c1, c2, c3, c4v);
            float d1 = selc((nib >> 4) & 0xF, c0, c1, c2, c3, c4v);
            float d2 = selc((nib >> 8) & 0xF, c0, c1, c2, c3, c4v);
            float d3 = selc((nib >> 12) & 0xF, c0, c1, c2, c3, c4v);
            if (!vec) {  // partial tile: zero OOB contributions
                if (i + 0 >= n) d0 = 0.0f;
                if (i + 1 >= n) d1 = 0.0f;
                if (i + 2 >= n) d2 = 0.0f;
                if (i + 3 >= n) d3 = 0.0f;
            }
            float e1 = d0, e2 = e1 + d1, e3 = e2 + d2, s = e3 + d3;

            // wave inclusive scan of per-thread sums
            float x = s;
#pragma unroll
            for (int off = 1; off < 64; off <<= 1) {
                float y = __shfl_up(x, off, 64);
                if (lane >= off) x += y;
            }
            if (lane == 63) wsum[tt & 1][wv] = x;
            __syncthreads();
            float w0 = wsum[tt & 1][0], w1 = wsum[tt & 1][1];
            float w2 = wsum[tt & 1][2], w3 = wsum[tt & 1][3];
            float waveOff = (wv > 0 ? w0 : 0.0f) + (wv > 1 ? w1 : 0.0f) +
                            (wv > 2 ? w2 : 0.0f);
            float total = w0 + w1 + w2 + w3;
            // no 2nd barrier: next tile uses the OTHER wsum slot (R7-proven)

            float b = running + waveOff + (x - s);  // exclusive prefix at i
            if (vec) {
                *reinterpret_cast<float4*>(out + i) =
                    make_float4(b, b + e1, b + e2, b + e3);
            } else {
                if (i + 0 < n) out[i + 0] = b;
                if (i + 1 < n) out[i + 1] = b + e1;
                if (i + 2 < n) out[i + 2] = b + e2;
                if (i + 3 < n) out[i + 3] = b + e3;
            }
            running += total;
        }
    }
    if (end == n && start < n && tid == 0) out[n] = running;
}

extern "C" void kernel_launch(void* const* d_in, const int* in_sizes, int n_in,
                              void* d_out, int out_size, void* d_ws, size_t ws_size,
                              hipStream_t stream) {
    const int* ann = (const int*)d_in[0];
    const float* org = (const float*)d_in[1];
    const float* bd = (const float*)d_in[2];
    const float* de = (const float*)d_in[3];
    const float* sa = (const float*)d_in[4];
    const float* in = (const float*)d_in[5];
    const float* bi = (const float*)d_in[6];
    float* out = (float*)d_out;

    long long n = (long long)in_sizes[0];
    int nb = (int)((n + CHUNK - 1) / CHUNK);  // 2048 for N=2^25
    if (nb < 1) nb = 1;

    // ws layout: bcT (nb*5 ints) | codes (nb*GROUPS*THREADS uint4, 256B-aligned)
    int* bcT = (int*)d_ws;
    size_t bct_bytes = ((size_t)nb * 5 * sizeof(int) + 255) & ~(size_t)255;
    uint4* c4 = (uint4*)((char*)d_ws + bct_bytes);

    k_pack<<<nb, THREADS, 0, stream>>>(ann, c4, bcT, n, nb);
    k_emit<<<nb, THREADS, 0, stream>>>(c4, bcT, out, n, nb, org, bd, de, sa,
                                       in, bi);
}

// Round 13
// 62.173 us; speedup vs baseline: 1.1283x; 1.0478x over previous
//
#include <hip/hip_runtime.h>

#define EPSF 0.01f
#define THREADS 256
#define WAVES (THREADS / 64)
#define TILE (THREADS * 4)   // 1024 elems: thread t -> 4 elems at tb+4t (coalesced)
#define TPB 16               // tiles per block -> chunk = 16384
#define CHUNK (TILE * TPB)
#define GROUPS 2             // 8 tiles per uint4 code group

typedef unsigned long long u64;
typedef unsigned int u32;

// Per-category change scalars, exactly as the reference computes them.
// jnp.clip(x, lo, hi) == min(max(x, lo), hi)
__device__ __forceinline__ void load_changes(const float* bd, const float* de,
                                             const float* sa, const float* in,
                                             const float* bi, float ch[5]) {
    float vbd = *bd, vd = *de, vs = *sa, vi = *in, vbi = *bi;
    ch[0] = fminf(vbd, fminf(0.0f, vd) - EPSF);
    ch[1] = fminf(fmaxf(vd, vbd + EPSF), 0.0f - EPSF);
    ch[2] = fminf(fmaxf(vs, vd + EPSF), vi - EPSF);
    ch[3] = fminf(fmaxf(vi, 0.0f + EPSF), vbi - EPSF);
    ch[4] = fmaxf(vbi, fmaxf(0.0f, vi) + EPSF);
}

// code 0..4 -> change; cmp+cndmask chain (no runtime-indexed array).
__device__ __forceinline__ float selc(u32 v, float c0, float c1, float c2,
                                      float c3, float c4) {
    return (v == 0) ? c0 : (v == 1) ? c1 : (v == 2) ? c2 : (v == 3) ? c3 : c4;
}

// Pass 1: read ann once (coalesced int4), emit 4-bit codes as uint4 per thread
// per 8-tile group (16 B/lane contiguous, 16.8 MB total) + exact per-block
// counts (12-bit packed fields, <=64/category/thread). Counts transposed
// bcT[c*nb+b]. Balanced traffic: 134 MB read + 17 MB write.
__global__ __launch_bounds__(THREADS) void k_pack(const int* __restrict__ ann,
                                                  uint4* __restrict__ c4,
                                                  int* __restrict__ bcT,
                                                  long long n, int nb) {
    const int tid = threadIdx.x, lane = tid & 63, wv = tid >> 6;
    const long long start = (long long)blockIdx.x * CHUNK;
    u64 pk = 0ull;

    for (int g = 0; g < GROUPS; ++g) {
        long long gb = start + (long long)g * (8 * TILE);
        if (gb >= n) break;  // block-uniform
        u32 w0 = 0, w1 = 0, w2 = 0, w3 = 0;
#pragma unroll
        for (int tt = 0; tt < 8; ++tt) {
            long long tb = gb + (long long)tt * TILE;
            if (tb >= n) break;  // block-uniform
            long long i = tb + (long long)tid * 4;
            u32 nib = 0;
            if (i + 4 <= n) {
                int4 a = *reinterpret_cast<const int4*>(ann + i);
                u32 cx = (u32)(a.x - 1), cy = (u32)(a.y - 1);
                u32 cz = (u32)(a.z - 1), cd = (u32)(a.w - 1);
                pk += (1ull << (cx * 12)) + (1ull << (cy * 12)) +
                      (1ull << (cz * 12)) + (1ull << (cd * 12));
                nib = cx | (cy << 4) | (cz << 8) | (cd << 12);
            } else {
#pragma unroll
                for (int j = 0; j < 4; ++j) {
                    if (i + j < n) {
                        u32 c = (u32)(ann[i + j] - 1);
                        pk += (1ull << (c * 12));
                        nib |= c << (4 * j);
                    }
                }
            }
            u32 sh = (tt & 1) * 16;
            if (tt < 2) w0 |= nib << sh;
            else if (tt < 4) w1 |= nib << sh;
            else if (tt < 6) w2 |= nib << sh;
            else w3 |= nib << sh;
        }
        c4[((long long)blockIdx.x * GROUPS + g) * THREADS + tid] =
            make_uint4(w0, w1, w2, w3);
    }

    int cnt[5];
#pragma unroll
    for (int c = 0; c < 5; ++c) cnt[c] = (int)((pk >> (c * 12)) & 0xFFFull);
    __shared__ int sred[WAVES][5];
#pragma unroll
    for (int c = 0; c < 5; ++c) {
        int s = cnt[c];
#pragma unroll
        for (int off = 32; off > 0; off >>= 1) s += __shfl_down(s, off, 64);
        if (lane == 0) sred[wv][c] = s;
    }
    __syncthreads();
    if (tid == 0) {
#pragma unroll
        for (int c = 0; c < 5; ++c)
            bcT[c * nb + blockIdx.x] =
                sred[0][c] + sred[1][c] + sred[2][c] + sred[3][c];
    }
}

// Pass 2: exact float base via redundant predecessor-count sum (40 KB,
// L2/IC-resident, fully parallel), then per tile: decode codes from registers,
// wave scan + double-buffered wsum (1 barrier/tile), coalesced float4
// exclusive-prefix store. Balanced traffic: 17 MB read (mostly cache-hit) +
// 134 MB write.
__global__ __launch_bounds__(THREADS) void k_emit(
    const uint4* __restrict__ c4, const int* __restrict__ bcT,
    float* __restrict__ out, long long n, int nb, const float* org,
    const float* bd, const float* de, const float* sa, const float* in,
    const float* bi) {
    float ch[5];
    load_changes(bd, de, sa, in, bi, ch);
    const float c0 = ch[0], c1 = ch[1], c2 = ch[2], c3 = ch[3], c4v = ch[4];

    __shared__ int sred[WAVES][5];
    __shared__ float wsum[2][WAVES];  // double-buffered: 1 barrier per tile
    __shared__ float s_base;

    const int tid = threadIdx.x, lane = tid & 63, wv = tid >> 6;
    const int vbid = blockIdx.x;

    // Phase A: base = org + sum_c (#cat_c before my chunk) * ch_c (exact ints)
    int pc[5];
#pragma unroll
    for (int c = 0; c < 5; ++c) {
        int s = 0;
        for (int j = tid; j < vbid; j += THREADS) s += bcT[c * nb + j];
#pragma unroll
        for (int off = 32; off > 0; off >>= 1) s += __shfl_down(s, off, 64);
        pc[c] = s;
    }
    if (lane == 0) {
#pragma unroll
        for (int c = 0; c < 5; ++c) sred[wv][c] = pc[c];
    }
    __syncthreads();
    if (tid == 0) {
        double acc = (double)(*org);
#pragma unroll
        for (int c = 0; c < 5; ++c) {
            int tot = sred[0][c] + sred[1][c] + sred[2][c] + sred[3][c];
            acc += (double)tot * (double)ch[c];
        }
        s_base = (float)acc;
    }
    __syncthreads();

    const long long start = (long long)vbid * CHUNK;
    long long end = start + CHUNK;
    if (end > n) end = n;
    float running = s_base;

    for (int g = 0; g < GROUPS; ++g) {
        long long gb = start + (long long)g * (8 * TILE);
        if (gb >= end) break;  // block-uniform
        uint4 cv = c4[((long long)vbid * GROUPS + g) * THREADS + tid];
#pragma unroll
        for (int tt = 0; tt < 8; ++tt) {
            long long tb = gb + (long long)tt * TILE;
            if (tb >= end) break;  // block-uniform
            long long i = tb + (long long)tid * 4;

            u32 w = (tt < 2) ? cv.x : (tt < 4) ? cv.y : (tt < 6) ? cv.z : cv.w;
            u32 nib = w >> ((tt & 1) * 16);
            const bool vec = (i + 4 <= n);
            float d0 = selc(nib & 0xF, c0, c1, c2, c3, c4v);
            float d1 = selc((nib >> 4) & 0xF, c0, c1, c2, c3, c4v);
            float d2 = selc((nib >> 8) & 0xF, c0, c1, c2, c3, c4v);
            float d3 = selc((nib >> 12) & 0xF, c0, c1, c2, c3, c4v);
            if (!vec) {  // partial tile: zero OOB contributions
                if (i + 0 >= n) d0 = 0.0f;
                if (i + 1 >= n) d1 = 0.0f;
                if (i + 2 >= n) d2 = 0.0f;
                if (i + 3 >= n) d3 = 0.0f;
            }
            float e1 = d0, e2 = e1 + d1, e3 = e2 + d2, s = e3 + d3;

            // wave inclusive scan of per-thread sums
            float x = s;
#pragma unroll
            for (int off = 1; off < 64; off <<= 1) {
                float y = __shfl_up(x, off, 64);
                if (lane >= off) x += y;
            }
            if (lane == 63) wsum[tt & 1][wv] = x;
            __syncthreads();
            float w0 = wsum[tt & 1][0], w1 = wsum[tt & 1][1];
            float w2 = wsum[tt & 1][2], w3 = wsum[tt & 1][3];
            float waveOff = (wv > 0 ? w0 : 0.0f) + (wv > 1 ? w1 : 0.0f) +
                            (wv > 2 ? w2 : 0.0f);
            float total = w0 + w1 + w2 + w3;
            // no 2nd barrier: next tile uses the OTHER wsum slot (R7-proven)

            float b = running + waveOff + (x - s);  // exclusive prefix at i
            if (vec) {
                *reinterpret_cast<float4*>(out + i) =
                    make_float4(b, b + e1, b + e2, b + e3);
            } else {
                if (i + 0 < n) out[i + 0] = b;
                if (i + 1 < n) out[i + 1] = b + e1;
                if (i + 2 < n) out[i + 2] = b + e2;
                if (i + 3 < n) out[i + 3] = b + e3;
            }
            running += total;
        }
    }
    if (end == n && start < n && tid == 0) out[n] = running;
}

extern "C" void kernel_launch(void* const* d_in, const int* in_sizes, int n_in,
                              void* d_out, int out_size, void* d_ws, size_t ws_size,
                              hipStream_t stream) {
    const int* ann = (const int*)d_in[0];
    const float* org = (const float*)d_in[1];
    const float* bd = (const float*)d_in[2];
    const float* de = (const float*)d_in[3];
    const float* sa = (const float*)d_in[4];
    const float* in = (const float*)d_in[5];
    const float* bi = (const float*)d_in[6];
    float* out = (float*)d_out;

    long long n = (long long)in_sizes[0];
    int nb = (int)((n + CHUNK - 1) / CHUNK);  // 2048 for N=2^25
    if (nb < 1) nb = 1;

    // ws layout: bcT (nb*5 ints) | codes (nb*GROUPS*THREADS uint4, 256B-aligned)
    int* bcT = (int*)d_ws;
    size_t bct_bytes = ((size_t)nb * 5 * sizeof(int) + 255) & ~(size_t)255;
    uint4* c4 = (uint4*)((char*)d_ws + bct_bytes);

    k_pack<<<nb, THREADS, 0, stream>>>(ann, c4, bcT, n, nb);
    k_emit<<<nb, THREADS, 0, stream>>>(c4, bcT, out, n, nb, org, bd, de, sa,
                                       in, bi);
}